// Round 14
// baseline (183.001 us; speedup 1.0000x reference)
//
#include <hip/hip_runtime.h>
#include <hip/hip_bf16.h>
#include <math.h>

#define BB 64
#define SS 128
#define C1 64
#define H1D 64
#define C2 128
#define H2D 32
#define FLAT 131072
#define NCOL 500
#define KCH 256      // split-K chunks in mgemm (deterministic partials, bf16)
#define KCSZ 512     // k per chunk  (KCH*KCSZ == FLAT)

typedef __attribute__((ext_vector_type(4))) float f32x4;
typedef __attribute__((ext_vector_type(8))) short bf16x8;

__device__ inline float bf2f(short s) {
    union { unsigned int u; float f; } z;
    z.u = ((unsigned int)(unsigned short)s) << 16;
    return z.f;
}

// ---------------- fused: prepw (blocks 0..511) + conv1 (blocks 512..1535) ----------------
__global__ __launch_bounds__(256) void k_conv1p(const float* __restrict__ x,
    const float* __restrict__ w, const float* __restrict__ bias,
    const float* __restrict__ w2,
    __hip_bfloat16* __restrict__ h1, __hip_bfloat16* __restrict__ Bw)
{
    int bid = blockIdx.x;
    if (bid < 512) {
      int i = bid*256 + threadIdx.x;             // 131072
      int jj = i & 7, oc = (i>>3)&127, kl8 = (i>>10)&31, stage = i>>15;
      int kl = kl8*8 + jj;
      int tap = kl >> 4, icl = kl & 15;
      int ic = stage*16 + icl;
      Bw[i] = __float2bfloat16(w2[(size_t)oc*1024 + ic*16 + tap]);
      return;
    }
    int tid = (bid - 512)*256 + threadIdx.x;     // (b, oh, ow)
    int ow = tid & 63, oh = (tid>>6)&63, bi = tid>>12;
    int ih0 = oh*2-1, iw0 = ow*2-1;
    float in[48];
    #pragma unroll
    for (int ic=0; ic<3; ic++)
      #pragma unroll
      for (int kh=0; kh<4; kh++)
        #pragma unroll
        for (int kw=0; kw<4; kw++) {
          int ih = ih0+kh, iw = iw0+kw;
          float v = 0.f;
          if ((unsigned)ih < 128u && (unsigned)iw < 128u)
            v = x[((size_t)(bi*3+ic)*SS + ih)*SS + iw];
          in[ic*16+kh*4+kw] = v;
        }
    #pragma unroll
    for (int g=0; g<4; g++) {
      __hip_bfloat16 outv[16];
      #pragma unroll
      for (int ocl=0; ocl<16; ocl++) {
        int oc = g*16 + ocl;
        float a = bias[oc];
        const float* wp = w + oc*48;             // wave-uniform -> scalar loads
        #pragma unroll
        for (int t=0; t<48; t++) a = fmaf(in[t], wp[t], a);
        a = a >= 0.f ? a : 0.2f*a;
        outv[ocl] = __float2bfloat16(a);
      }
      __hip_bfloat16* dst = h1 + (((size_t)g*BB + bi)*4096 + oh*64 + ow)*16;
      *(bf16x8*)(dst)     = *(bf16x8*)&outv[0];
      *(bf16x8*)(dst + 8) = *(bf16x8*)&outv[8];
    }
}

// ---------------- conv2 MFMA implicit GEMM, full-width N=128 ----------------
// 512 blocks = bi(64) x strip8(8); block covers 4 oh rows x 32 ow x 128 oc.
// Wave wv owns oh row strip8*4+wv; acc[2 mf][8 nf].  Staging once per block
// (R12's nh-pair duplication removed: -45% LDS staging work).
__global__ __launch_bounds__(256) void k_conv2(const __hip_bfloat16* __restrict__ h1,
    const __hip_bfloat16* __restrict__ Bw, const float* __restrict__ b2,
    __hip_bfloat16* __restrict__ h2b, double* __restrict__ bnp2)
{
    int bid = blockIdx.x;                        // bi*8 + strip8
    int bi = bid >> 3, strip8 = bid & 7;
    int lane = threadIdx.x & 63, wv = threadIdx.x >> 6;
    int l15 = lane & 15, kg = lane >> 4;

    __shared__ __align__(16) short tile[660*24];     // 31 KB (20 row48 x 33 x 24)
    __shared__ float2 bnl[8][16][16];                // 16 KB

    f32x4 acc[2][8];
    #pragma unroll
    for (int m=0;m<2;m++)
      #pragma unroll
      for (int n=0;n<8;n++) acc[m][n] = (f32x4)(0.f);

    int ihb = strip8*8 - 1;                      // global ih of ih_l=0

    for (int stage=0; stage<4; ++stage) {
      const __hip_bfloat16* hsrc = h1 + ((size_t)stage*BB + bi)*4096*16;
      for (int idx = threadIdx.x; idx < 1320; idx += 256) {
        int half = idx & 1, p = idx >> 1;        // p = ih_l*66 + iw_l, p in [0,660)
        int ih_l = p / 66, iw_l = p - ih_l*66;
        int ih = ihb + ih_l, iw = iw_l - 1;
        int row48 = (ih_l*2 + (iw_l&1))*33 + (iw_l>>1);
        bf16x8 v = (bf16x8)(0);
        if ((unsigned)ih < 64u && (unsigned)iw < 64u)
          v = *(const bf16x8*)(hsrc + ((size_t)(ih*64+iw)*16 + half*8));
        *(bf16x8*)&tile[row48*24 + half*8] = v;
      }
      __syncthreads();
      const __hip_bfloat16* bwst = Bw + (size_t)stage*32*128*8;
      #pragma unroll
      for (int j=0; j<8; j++) {
        bf16x8 bf[8];
        #pragma unroll
        for (int nf=0; nf<8; nf++)
          bf[nf] = *(const bf16x8*)(bwst + ((size_t)((j*4+kg)*128) + nf*16 + l15)*8);
        int tap = 2*j + (kg>>1);
        int kh = tap>>2, kw = tap&3;
        int icl0 = (kg&1)*8;
        bf16x8 af[2];
        #pragma unroll
        for (int mf=0; mf<2; mf++) {
          int ow   = mf*16 + l15;                // A row r = l15
          int ih_l = 2*wv + kh;                  // oh_l = wv
          int iw_l = 2*ow + kw;
          int row48 = (ih_l*2 + (iw_l&1))*33 + (iw_l>>1);
          af[mf] = *(const bf16x8*)&tile[row48*24 + icl0];
        }
        #pragma unroll
        for (int mf=0; mf<2; mf++)
          #pragma unroll
          for (int nf=0; nf<8; nf++)
            acc[mf][nf] = __builtin_amdgcn_mfma_f32_16x16x32_bf16(af[mf], bf[nf], acc[mf][nf], 0, 0, 0);
      }
      __syncthreads();
    }
    // epilogue: D row = kg*4+q -> ow = mf*16+kg*4+q ; D col = l15 -> oc = nf*16+l15
    #pragma unroll
    for (int nf=0; nf<8; nf++) {
      int oc = nf*16 + l15;
      float bv = b2[oc];
      float s1 = 0.f, s2 = 0.f;
      #pragma unroll
      for (int mf=0; mf<2; mf++) {
        float v0 = acc[mf][nf][0] + bv;
        float v1 = acc[mf][nf][1] + bv;
        float v2 = acc[mf][nf][2] + bv;
        float v3 = acc[mf][nf][3] + bv;
        s1 += v0+v1+v2+v3;
        s2 = fmaf(v0,v0, fmaf(v1,v1, fmaf(v2,v2, fmaf(v3,v3, s2))));
        __hip_bfloat16 o4[4];
        o4[0] = __float2bfloat16(v0); o4[1] = __float2bfloat16(v1);
        o4[2] = __float2bfloat16(v2); o4[3] = __float2bfloat16(v3);
        *(double*)&h2b[((size_t)bi*C2 + oc)*1024 + (strip8*4+wv)*32 + mf*16 + kg*4] = *(double*)o4;
      }
      bnl[nf][wv*4+kg][l15] = make_float2(s1, s2);
    }
    __syncthreads();
    if (threadIdx.x < 128) {
      int nf = threadIdx.x >> 4, l = threadIdx.x & 15;
      double s1 = 0.0, s2 = 0.0;
      #pragma unroll
      for (int i=0;i<16;i++) {
        float2 v = bnl[nf][i][l];
        s1 += (double)v.x; s2 += (double)v.y;
      }
      int oc = nf*16 + l;                        // 0..127
      bnp2[(size_t)oc*512 + bid]         = s1;   // s1 bank [0, 65536)
      bnp2[65536 + (size_t)oc*512 + bid] = s2;   // s2 bank [65536, 131072)
    }
}

// ---------------- fused: mgemm (blocks 0..1023) + final1 (blocks 1024..1535) ----------------
__global__ __launch_bounds__(256) void k_mgf(const __hip_bfloat16* __restrict__ h2b,
    const double* __restrict__ bnp2, const float* __restrict__ gamma,
    const float* __restrict__ beta, const float* __restrict__ T,
    const float* __restrict__ lw,
    __hip_bfloat16* __restrict__ Mpart, double* __restrict__ fpart)
{
    __shared__ __align__(16) char smem[38432];
    int t = threadIdx.x;
    int bid = blockIdx.x;

    if (bid < 1024) {
      // ================= mgemm path =================
      int lane = t & 63, wv = t >> 6;
      int l15 = lane & 15, kg = lane >> 4;
      int xc = bid & 7, j = bid >> 3;
      int kc = xc*32 + (j >> 2);
      int ng = j & 3;
      int k0b = kc * KCSZ;
      int ch = kc >> 1;

      // inline BN stats for channel ch (512 partials)
      double* r1 = (double*)(smem + 34304);
      double* r2 = (double*)(smem + 34304 + 2048);
      float*  stf = (float*)(smem + 34304 + 4096);
      r1[t] = bnp2[(size_t)ch*512 + t] + bnp2[(size_t)ch*512 + 256 + t];
      r2[t] = bnp2[65536 + (size_t)ch*512 + t] + bnp2[65536 + (size_t)ch*512 + 256 + t];
      __syncthreads();
      for (int st = 128; st > 0; st >>= 1) {
        if (t < st) { r1[t] += r1[t+st]; r2[t] += r2[t+st]; }
        __syncthreads();
      }
      if (t == 0) {
        double mean = r1[0] * (1.0/65536.0);
        double var  = r2[0] * (1.0/65536.0) - mean*mean;
        double rstd = 1.0 / sqrt(var + 1e-5);
        double scd  = rstd * (double)gamma[ch];
        stf[0] = (float)scd;
        stf[1] = (float)((double)beta[ch] - mean*scd);
      }
      __syncthreads();
      float sc = stf[0], sh = stf[1];

      typedef float TsRow[134];
      TsRow* Ts0 = (TsRow*)smem;          // Ts[2][32][134] overlay
      TsRow* Ts1 = (TsRow*)(smem + 32*134*4);

      int f4c = t & 31, rbase = t >> 5;
      int cols4 = ng*128 + f4c*4;
      bool cvalid = cols4 < 500;

      f32x4 acc[4][2];
      #pragma unroll
      for (int m=0;m<4;m++) { acc[m][0] = (f32x4)(0.f); acc[m][1] = (f32x4)(0.f); }

      float4 tv0, tv1, tv2, tv3;
      {
        int ks0 = k0b;
        tv0 = cvalid ? *(const float4*)&T[(size_t)(ks0+rbase   )*NCOL + cols4] : make_float4(0,0,0,0);
        tv1 = cvalid ? *(const float4*)&T[(size_t)(ks0+rbase+ 8)*NCOL + cols4] : make_float4(0,0,0,0);
        tv2 = cvalid ? *(const float4*)&T[(size_t)(ks0+rbase+16)*NCOL + cols4] : make_float4(0,0,0,0);
        tv3 = cvalid ? *(const float4*)&T[(size_t)(ks0+rbase+24)*NCOL + cols4] : make_float4(0,0,0,0);
        float* d0 = &Ts0[rbase   ][f4c*4];
        float* d1 = &Ts0[rbase+ 8][f4c*4];
        float* d2 = &Ts0[rbase+16][f4c*4];
        float* d3 = &Ts0[rbase+24][f4c*4];
        *(float2*)d0 = make_float2(tv0.x,tv0.y); *(float2*)(d0+2) = make_float2(tv0.z,tv0.w);
        *(float2*)d1 = make_float2(tv1.x,tv1.y); *(float2*)(d1+2) = make_float2(tv1.z,tv1.w);
        *(float2*)d2 = make_float2(tv2.x,tv2.y); *(float2*)(d2+2) = make_float2(tv2.z,tv2.w);
        *(float2*)d3 = make_float2(tv3.x,tv3.y); *(float2*)(d3+2) = make_float2(tv3.z,tv3.w);
      }
      __syncthreads();

      for (int s = 0; s < 16; s++) {
        TsRow* Tc = (s & 1) ? Ts1 : Ts0;
        TsRow* Tn = (s & 1) ? Ts0 : Ts1;
        if (s < 15) {
          int ks0 = k0b + (s+1)*32;
          tv0 = cvalid ? *(const float4*)&T[(size_t)(ks0+rbase   )*NCOL + cols4] : make_float4(0,0,0,0);
          tv1 = cvalid ? *(const float4*)&T[(size_t)(ks0+rbase+ 8)*NCOL + cols4] : make_float4(0,0,0,0);
          tv2 = cvalid ? *(const float4*)&T[(size_t)(ks0+rbase+16)*NCOL + cols4] : make_float4(0,0,0,0);
          tv3 = cvalid ? *(const float4*)&T[(size_t)(ks0+rbase+24)*NCOL + cols4] : make_float4(0,0,0,0);
        }
        {
          int k0 = k0b + s*32;
          bf16x8 af[4];
          #pragma unroll
          for (int mf=0; mf<4; mf++) {
            bf16x8 raw = *(const bf16x8*)(h2b + (size_t)(mf*16 + l15)*FLAT + k0 + kg*8);
            __hip_bfloat16 ta[8];
            #pragma unroll
            for (int jj=0; jj<8; jj++) {
              float f = fmaf(bf2f(raw[jj]), sc, sh);
              f = f >= 0.f ? f : 0.2f*f;
              ta[jj] = __float2bfloat16(f);
            }
            af[mf] = *(bf16x8*)ta;
          }
          bf16x8 bfr[2];
          #pragma unroll
          for (int nf=0; nf<2; nf++) {
            int c = wv*32 + nf*16 + l15;
            __hip_bfloat16 tb[8];
            #pragma unroll
            for (int jj=0; jj<8; jj++)
              tb[jj] = __float2bfloat16(Tc[kg*8+jj][c]);
            bfr[nf] = *(bf16x8*)tb;
          }
          #pragma unroll
          for (int mf=0;mf<4;mf++)
            #pragma unroll
            for (int nf=0;nf<2;nf++)
              acc[mf][nf] = __builtin_amdgcn_mfma_f32_16x16x32_bf16(af[mf], bfr[nf], acc[mf][nf], 0, 0, 0);
        }
        __syncthreads();
        if (s < 15) {
          float* d0 = &Tn[rbase   ][f4c*4];
          float* d1 = &Tn[rbase+ 8][f4c*4];
          float* d2 = &Tn[rbase+16][f4c*4];
          float* d3 = &Tn[rbase+24][f4c*4];
          *(float2*)d0 = make_float2(tv0.x,tv0.y); *(float2*)(d0+2) = make_float2(tv0.z,tv0.w);
          *(float2*)d1 = make_float2(tv1.x,tv1.y); *(float2*)(d1+2) = make_float2(tv1.z,tv1.w);
          *(float2*)d2 = make_float2(tv2.x,tv2.y); *(float2*)(d2+2) = make_float2(tv2.z,tv2.w);
          *(float2*)d3 = make_float2(tv3.x,tv3.y); *(float2*)(d3+2) = make_float2(tv3.z,tv3.w);
          __syncthreads();
        }
      }
      __hip_bfloat16* op = Mpart + (size_t)(kc*4 + ng)*8192;
      #pragma unroll
      for (int mf=0; mf<4; mf++) {
        __hip_bfloat16 buf[8];
        #pragma unroll
        for (int nf=0; nf<2; nf++)
          #pragma unroll
          for (int q=0; q<4; q++)
            buf[nf*4+q] = __float2bfloat16(acc[mf][nf][q]);
        *(bf16x8*)(op + ((size_t)mf*256 + t)*8) = *(bf16x8*)buf;
      }
      return;
    }

    // ================= final1 path =================
    int bx = bid - 1024;          // 0..511 = b*8 + s
    int b = bx >> 3, s = bx & 7;
    double* rA = (double*)smem;                 // [16][16] s1 partials
    double* rB = (double*)(smem + 2048);        // [16][16] s2 partials
    float*  scs = (float*)(smem + 4096);        // 16 floats
    float*  shs = (float*)(smem + 4096 + 64);   // 16 floats
    double* red = (double*)(smem + 8192);       // 256 doubles
    {
      int cl = t >> 4, i = t & 15;
      int c = s*16 + cl;
      double a1 = 0.0, a2 = 0.0;
      #pragma unroll
      for (int q=0;q<32;q++) {
        a1 += bnp2[(size_t)c*512 + i*32 + q];
        a2 += bnp2[65536 + (size_t)c*512 + i*32 + q];
      }
      rA[cl*16+i] = a1; rB[cl*16+i] = a2;
      __syncthreads();
      for (int st = 8; st > 0; st >>= 1) {
        if (i < st) { rA[cl*16+i] += rA[cl*16+i+st]; rB[cl*16+i] += rB[cl*16+i+st]; }
        __syncthreads();
      }
      if (i == 0) {
        double mean = rA[cl*16] * (1.0/65536.0);
        double var  = rB[cl*16] * (1.0/65536.0) - mean*mean;
        double rstd = 1.0 / sqrt(var + 1e-5);
        double scd  = rstd * (double)gamma[c];
        scs[cl] = (float)scd;
        shs[cl] = (float)((double)beta[c] - mean*scd);
      }
      __syncthreads();
    }
    const __hip_bfloat16* hp = h2b + (size_t)b*FLAT;
    double acc = 0.0;
    for (int g = s*2048 + t; g < (s+1)*2048; g += 256) {  // bf16x8 groups
      int k = g*8;
      int cl = (k >> 10) & 15;
      float sc = scs[cl], sh = shs[cl];
      bf16x8 v = *(const bf16x8*)&hp[k];
      float4 w0 = *(const float4*)&lw[k];
      float4 w1 = *(const float4*)&lw[k+4];
      float f0 = fmaf(bf2f(v[0]), sc, sh); f0 = f0>=0.f?f0:0.2f*f0;
      float f1 = fmaf(bf2f(v[1]), sc, sh); f1 = f1>=0.f?f1:0.2f*f1;
      float f2 = fmaf(bf2f(v[2]), sc, sh); f2 = f2>=0.f?f2:0.2f*f2;
      float f3 = fmaf(bf2f(v[3]), sc, sh); f3 = f3>=0.f?f3:0.2f*f3;
      float f4 = fmaf(bf2f(v[4]), sc, sh); f4 = f4>=0.f?f4:0.2f*f4;
      float f5 = fmaf(bf2f(v[5]), sc, sh); f5 = f5>=0.f?f5:0.2f*f5;
      float f6 = fmaf(bf2f(v[6]), sc, sh); f6 = f6>=0.f?f6:0.2f*f6;
      float f7 = fmaf(bf2f(v[7]), sc, sh); f7 = f7>=0.f?f7:0.2f*f7;
      acc = fma((double)f0, (double)w0.x, acc);
      acc = fma((double)f1, (double)w0.y, acc);
      acc = fma((double)f2, (double)w0.z, acc);
      acc = fma((double)f3, (double)w0.w, acc);
      acc = fma((double)f4, (double)w1.x, acc);
      acc = fma((double)f5, (double)w1.y, acc);
      acc = fma((double)f6, (double)w1.z, acc);
      acc = fma((double)f7, (double)w1.w, acc);
    }
    red[t] = acc;
    __syncthreads();
    for (int st = 128; st > 0; st >>= 1) {
      if (t < st) red[t] += red[t + st];
      __syncthreads();
    }
    if (t == 0) fpart[bx] = red[0];
}

// ---------------- mreduce stage A: coalesced 8-chunk partial sums -> Mpart2 fp32 ----------------
__global__ __launch_bounds__(256) void k_mreduceA(const __hip_bfloat16* __restrict__ Mpart,
    float* __restrict__ Mpart2)
{
    int ng = blockIdx.x & 3, kg8 = blockIdx.x >> 2;
    int t = threadIdx.x;
    f32x4 a0[4], a1[4];
    #pragma unroll
    for (int mf=0; mf<4; mf++) { a0[mf] = (f32x4)(0.f); a1[mf] = (f32x4)(0.f); }
    #pragma unroll
    for (int kcl=0; kcl<8; kcl++) {
      int kc = kg8*8 + kcl;
      const __hip_bfloat16* ch = Mpart + (size_t)(kc*4 + ng)*8192;
      #pragma unroll
      for (int mf=0; mf<4; mf++) {
        bf16x8 v = *(const bf16x8*)(ch + ((size_t)mf*256 + t)*8);
        a0[mf][0] += bf2f(v[0]); a0[mf][1] += bf2f(v[1]);
        a0[mf][2] += bf2f(v[2]); a0[mf][3] += bf2f(v[3]);
        a1[mf][0] += bf2f(v[4]); a1[mf][1] += bf2f(v[5]);
        a1[mf][2] += bf2f(v[6]); a1[mf][3] += bf2f(v[7]);
      }
    }
    #pragma unroll
    for (int mf=0; mf<4; mf++) {
      float* dst = Mpart2 + ((size_t)(ng*32 + kg8)*4 + mf)*2048 + t*8;
      *(f32x4*)dst = a0[mf];
      *(f32x4*)(dst+4) = a1[mf];
    }
}

// ---------------- minibatch discrimination: o_b ----------------
__global__ __launch_bounds__(256) void k_ob(const float* __restrict__ Mpart2,
    float* __restrict__ ob)
{
    int o = blockIdx.x;   // 0..99
    __shared__ float Ms[320];
    __shared__ float red[256];
    for (int idx = threadIdx.x; idx < 320; idx += 256) {
      int a = idx / 5, d = idx - a*5;
      int r = a, c = o*5 + d;
      int mf = r >> 4, kg = (r >> 2) & 3, q = r & 3;
      int ng = c >> 7, wv = (c >> 5) & 3, nf = (c >> 4) & 1, l15 = c & 15;
      int t = wv*64 + kg*16 + l15, j8 = nf*4 + q;
      const float* p = Mpart2 + ((size_t)(ng*32)*4 + mf)*2048 + t*8 + j8;
      float s = 0.f;
      #pragma unroll 8
      for (int kg8 = 0; kg8 < 32; kg8++) s += p[(size_t)kg8*8192];
      Ms[idx] = s;
    }
    __syncthreads();
    int b = threadIdx.x & 63, aq = threadIdx.x >> 6;
    float s = 0.f;
    for (int a = aq*16; a < aq*16+16; a++) {
      float n = 0.f;
      #pragma unroll
      for (int d=0; d<5; d++) n += fabsf(Ms[a*5+d] - Ms[b*5+d]);
      s += expf(-n);
    }
    red[threadIdx.x] = s;
    __syncthreads();
    if (threadIdx.x < 64)
      ob[(size_t)b*100 + o] = red[b] + red[64+b] + red[128+b] + red[192+b];
}

__global__ void k_final2(const double* __restrict__ fpart,
    const float* __restrict__ ob, const float* __restrict__ lw,
    const float* __restrict__ lb, float* __restrict__ out)
{
    int b = threadIdx.x;   // 64 threads, 1 block
    double s = 0.0;
    #pragma unroll
    for (int i = 0; i < 8; i++) s += fpart[b*8 + i];
    for (int o = 0; o < 100; o++)
      s = fma((double)ob[(size_t)b*100 + o], (double)lw[FLAT + o], s);
    s += (double)lb[0];
    out[b] = (float)(1.0 / (1.0 + exp(-s)));
}

extern "C" void kernel_launch(void* const* d_in, const int* in_sizes, int n_in,
                              void* d_out, int out_size, void* d_ws, size_t ws_size,
                              hipStream_t stream)
{
    const float* x   = (const float*)d_in[0];
    const float* w1  = (const float*)d_in[1];
    const float* b1  = (const float*)d_in[2];
    const float* w2  = (const float*)d_in[3];
    const float* b2  = (const float*)d_in[4];
    const float* gam = (const float*)d_in[5];
    const float* bet = (const float*)d_in[6];
    const float* T   = (const float*)d_in[7];
    const float* lw  = (const float*)d_in[8];
    const float* lb  = (const float*)d_in[9];
    float* out = (float*)d_out;

    float* ws = (float*)d_ws;
    // Layout (float offsets), ws ~1GB:
    //   [0 .. 8,388,608)            h1 bf16 -> later Mpart bf16 [1024][8192]
    //   [8,388,608 .. 12,582,912)   h2b bf16 [64][131072]
    //   [12,582,912 .. 12,648,448)  Bw bf16
    //   [12,648,704 .. 12,655,104)  ob (6400 f32)
    //   [12,655,104 .. 13,703,680)  Mpart2 (1,048,576 f32)
    //   [13,703,680 .. 13,965,824)  bnp2 (131,072 doubles: s1 [0,65536), s2 [65536,131072))
    //   [13,965,824 .. +1024)       fpart (512 doubles)
    __hip_bfloat16* h1 = (__hip_bfloat16*)ws;
    __hip_bfloat16* Mpart = (__hip_bfloat16*)ws;      // aliases h1 (dead after conv2)
    __hip_bfloat16* h2b = (__hip_bfloat16*)(ws + 8388608);
    __hip_bfloat16* Bw  = (__hip_bfloat16*)(ws + 12582912);
    float* ob    = ws + 12648704;
    float* Mpart2 = ws + 12655104;
    double* bnp2  = (double*)(ws + 13703680);
    double* fpart = (double*)(ws + 13965824);

    k_conv1p<<<1536, 256, 0, stream>>>(x, w1, b1, w2, h1, Bw);
    k_conv2<<<512, 256, 0, stream>>>(h1, Bw, b2, h2b, bnp2);
    k_mgf<<<1536, 256, 0, stream>>>(h2b, bnp2, gam, bet, T, lw, Mpart, fpart);
    k_mreduceA<<<128, 256, 0, stream>>>(Mpart, Mpart2);
    k_ob<<<100, 256, 0, stream>>>(Mpart2, ob);
    k_final2<<<1, 64, 0, stream>>>(fpart, ob, lw, lb, out);
}

// Round 15
// 179.306 us; speedup vs baseline: 1.0206x; 1.0206x over previous
//
#include <hip/hip_runtime.h>
#include <hip/hip_bf16.h>
#include <math.h>

#define BB 64
#define SS 128
#define C1 64
#define H1D 64
#define C2 128
#define H2D 32
#define FLAT 131072
#define NCOL 500
#define KCH 256      // split-K chunks in mgemm (deterministic partials, bf16)
#define KCSZ 512     // k per chunk  (KCH*KCSZ == FLAT)

typedef __attribute__((ext_vector_type(4))) float f32x4;
typedef __attribute__((ext_vector_type(8))) short bf16x8;

__device__ inline float bf2f(short s) {
    union { unsigned int u; float f; } z;
    z.u = ((unsigned int)(unsigned short)s) << 16;
    return z.f;
}

__device__ inline void st_bf4(short* dst, float4 v) {
    __hip_bfloat16 b[4];
    b[0] = __float2bfloat16(v.x); b[1] = __float2bfloat16(v.y);
    b[2] = __float2bfloat16(v.z); b[3] = __float2bfloat16(v.w);
    *(double*)dst = *(double*)b;
}

// ---------------- fused: prepw (blocks 0..511) + conv1 (blocks 512..1535) ----------------
__global__ __launch_bounds__(256) void k_conv1p(const float* __restrict__ x,
    const float* __restrict__ w, const float* __restrict__ bias,
    const float* __restrict__ w2,
    __hip_bfloat16* __restrict__ h1, __hip_bfloat16* __restrict__ Bw)
{
    int bid = blockIdx.x;
    if (bid < 512) {
      int i = bid*256 + threadIdx.x;             // 131072
      int jj = i & 7, oc = (i>>3)&127, kl8 = (i>>10)&31, stage = i>>15;
      int kl = kl8*8 + jj;
      int tap = kl >> 4, icl = kl & 15;
      int ic = stage*16 + icl;
      Bw[i] = __float2bfloat16(w2[(size_t)oc*1024 + ic*16 + tap]);
      return;
    }
    int tid = (bid - 512)*256 + threadIdx.x;     // (b, oh, ow)
    int ow = tid & 63, oh = (tid>>6)&63, bi = tid>>12;
    int ih0 = oh*2-1, iw0 = ow*2-1;
    float in[48];
    #pragma unroll
    for (int ic=0; ic<3; ic++)
      #pragma unroll
      for (int kh=0; kh<4; kh++)
        #pragma unroll
        for (int kw=0; kw<4; kw++) {
          int ih = ih0+kh, iw = iw0+kw;
          float v = 0.f;
          if ((unsigned)ih < 128u && (unsigned)iw < 128u)
            v = x[((size_t)(bi*3+ic)*SS + ih)*SS + iw];
          in[ic*16+kh*4+kw] = v;
        }
    #pragma unroll
    for (int g=0; g<4; g++) {
      __hip_bfloat16 outv[16];
      #pragma unroll
      for (int ocl=0; ocl<16; ocl++) {
        int oc = g*16 + ocl;
        float a = bias[oc];
        const float* wp = w + oc*48;             // wave-uniform -> scalar loads
        #pragma unroll
        for (int t=0; t<48; t++) a = fmaf(in[t], wp[t], a);
        a = a >= 0.f ? a : 0.2f*a;
        outv[ocl] = __float2bfloat16(a);
      }
      __hip_bfloat16* dst = h1 + (((size_t)g*BB + bi)*4096 + oh*64 + ow)*16;
      *(bf16x8*)(dst)     = *(bf16x8*)&outv[0];
      *(bf16x8*)(dst + 8) = *(bf16x8*)&outv[8];
    }
}

// ---------------- conv2 MFMA implicit GEMM -> h2b bf16; + per-block BN partials ----------------
// (R12 structure restored: nh-pair XCD sharing; R13's full-width variant doubled
//  inner-loop L2 B-traffic and regressed 164->183.)
__global__ __launch_bounds__(256) void k_conv2(const __hip_bfloat16* __restrict__ h1,
    const __hip_bfloat16* __restrict__ Bw, const float* __restrict__ b2,
    __hip_bfloat16* __restrict__ h2b, double* __restrict__ bnp2)
{
    int bid = blockIdx.x;
    int nh = (bid >> 3) & 1;
    int pair = (bid >> 4)*8 + (bid & 7);         // 0..255
    int bi = pair >> 2, strip = pair & 3;
    int lane = threadIdx.x & 63, wv = threadIdx.x >> 6;
    int l15 = lane & 15, kg = lane >> 4;

    __shared__ __align__(16) short tile[36*33*24];   // 57 KB
    __shared__ float2 bnl[4][16][16];                // 8 KB

    f32x4 acc[4][4];
    #pragma unroll
    for (int m=0;m<4;m++)
      #pragma unroll
      for (int n=0;n<4;n++) acc[m][n] = (f32x4)(0.f);

    int ihb = strip*16 - 1;

    for (int stage=0; stage<4; ++stage) {
      const __hip_bfloat16* hsrc = h1 + ((size_t)stage*BB + bi)*4096*16;
      for (int idx = threadIdx.x; idx < 2376; idx += 256) {
        int half = idx & 1, p = idx >> 1;        // p = ih_l*66 + iw_l
        int ih_l = p / 66, iw_l = p - ih_l*66;
        int ih = ihb + ih_l, iw = iw_l - 1;
        int row48 = (ih_l*2 + (iw_l&1))*33 + (iw_l>>1);
        bf16x8 v = (bf16x8)(0);
        if ((unsigned)ih < 64u && (unsigned)iw < 64u)
          v = *(const bf16x8*)(hsrc + ((size_t)(ih*64+iw)*16 + half*8));
        *(bf16x8*)&tile[row48*24 + half*8] = v;
      }
      __syncthreads();
      const __hip_bfloat16* bwst = Bw + (size_t)stage*32*128*8;
      #pragma unroll
      for (int j=0; j<8; j++) {
        bf16x8 bf[4];
        #pragma unroll
        for (int nf=0; nf<4; nf++)
          bf[nf] = *(const bf16x8*)(bwst + ((size_t)((j*4+kg)*128) + nh*64 + nf*16 + l15)*8);
        int tap = 2*j + (kg>>1);
        int kh = tap>>2, kw = tap&3;
        int icl0 = (kg&1)*8;
        bf16x8 af[4];
        #pragma unroll
        for (int mf=0; mf<4; mf++) {
          int oh_l = 2*wv + (mf>>1);
          int ow   = (mf&1)*16 + l15;
          int ih_l = 2*oh_l + kh;
          int iw_l = 2*ow + kw;
          int row48 = (ih_l*2 + (iw_l&1))*33 + (iw_l>>1);
          af[mf] = *(const bf16x8*)&tile[row48*24 + icl0];
        }
        #pragma unroll
        for (int mf=0; mf<4; mf++)
          #pragma unroll
          for (int nf=0; nf<4; nf++)
            acc[mf][nf] = __builtin_amdgcn_mfma_f32_16x16x32_bf16(af[mf], bf[nf], acc[mf][nf], 0, 0, 0);
      }
      __syncthreads();
    }
    #pragma unroll
    for (int nf=0; nf<4; nf++) {
      int oc = nh*64 + nf*16 + l15;
      float bv = b2[oc];
      float s1 = 0.f, s2 = 0.f;
      #pragma unroll
      for (int mf=0; mf<4; mf++) {
        int p0 = wv*64 + mf*16 + kg*4;
        float v0 = acc[mf][nf][0] + bv;
        float v1 = acc[mf][nf][1] + bv;
        float v2 = acc[mf][nf][2] + bv;
        float v3 = acc[mf][nf][3] + bv;
        s1 += v0+v1+v2+v3;
        s2 = fmaf(v0,v0, fmaf(v1,v1, fmaf(v2,v2, fmaf(v3,v3, s2))));
        __hip_bfloat16 o4[4];
        o4[0] = __float2bfloat16(v0); o4[1] = __float2bfloat16(v1);
        o4[2] = __float2bfloat16(v2); o4[3] = __float2bfloat16(v3);
        *(double*)&h2b[((size_t)bi*C2 + oc)*1024 + strip*256 + p0] = *(double*)o4;
      }
      bnl[nf][wv*4+kg][l15] = make_float2(s1, s2);
    }
    __syncthreads();
    if (threadIdx.x < 64) {
      int nf = threadIdx.x >> 4, l = threadIdx.x & 15;
      double s1 = 0.0, s2 = 0.0;
      #pragma unroll
      for (int i=0;i<16;i++) {
        float2 v = bnl[nf][i][l];
        s1 += (double)v.x; s2 += (double)v.y;
      }
      int oc = nh*64 + nf*16 + l;                // 0..127
      bnp2[(size_t)oc*256 + pair]         = s1;  // s1 bank [0,32768)
      bnp2[32768 + (size_t)oc*256 + pair] = s2;  // s2 bank [32768,65536)
    }
}

// ---------------- fused: mgemm (blocks 0..1023) + final1 (blocks 1024..1535) ----------------
// mgemm change vs R12: T staged in LDS as bf16 (cvt moved to staging side, same
// op count, identical numerics) -> smem 38.4KB -> 21.5KB -> higher occupancy.
__global__ __launch_bounds__(256) void k_mgf(const __hip_bfloat16* __restrict__ h2b,
    const double* __restrict__ bnp2, const float* __restrict__ gamma,
    const float* __restrict__ beta, const float* __restrict__ T,
    const float* __restrict__ lw,
    __hip_bfloat16* __restrict__ Mpart, double* __restrict__ fpart)
{
    __shared__ __align__(16) char smem[21504];
    int t = threadIdx.x;
    int bid = blockIdx.x;

    if (bid < 1024) {
      // ================= mgemm path =================
      int lane = t & 63, wv = t >> 6;
      int l15 = lane & 15, kg = lane >> 4;
      int xc = bid & 7, j = bid >> 3;
      int kc = xc*32 + (j >> 2);
      int ng = j & 3;
      int k0b = kc * KCSZ;
      int ch = kc >> 1;

      // inline BN stats for channel ch
      double* r1 = (double*)(smem + 17152);
      double* r2 = (double*)(smem + 17152 + 2048);
      float*  stf = (float*)(smem + 17152 + 4096);
      r1[t] = bnp2[(size_t)ch*256 + t];
      r2[t] = bnp2[32768 + (size_t)ch*256 + t];
      __syncthreads();
      for (int st = 128; st > 0; st >>= 1) {
        if (t < st) { r1[t] += r1[t+st]; r2[t] += r2[t+st]; }
        __syncthreads();
      }
      if (t == 0) {
        double mean = r1[0] * (1.0/65536.0);
        double var  = r2[0] * (1.0/65536.0) - mean*mean;
        double rstd = 1.0 / sqrt(var + 1e-5);
        double scd  = rstd * (double)gamma[ch];
        stf[0] = (float)scd;
        stf[1] = (float)((double)beta[ch] - mean*scd);
      }
      __syncthreads();
      float sc = stf[0], sh = stf[1];

      typedef short TsRow[134];
      TsRow* Ts0 = (TsRow*)smem;                 // bf16 [32][134]
      TsRow* Ts1 = (TsRow*)(smem + 8576);

      int f4c = t & 31, rbase = t >> 5;
      int cols4 = ng*128 + f4c*4;
      bool cvalid = cols4 < 500;

      f32x4 acc[4][2];
      #pragma unroll
      for (int m=0;m<4;m++) { acc[m][0] = (f32x4)(0.f); acc[m][1] = (f32x4)(0.f); }

      float4 tv0, tv1, tv2, tv3;
      {
        int ks0 = k0b;
        tv0 = cvalid ? *(const float4*)&T[(size_t)(ks0+rbase   )*NCOL + cols4] : make_float4(0,0,0,0);
        tv1 = cvalid ? *(const float4*)&T[(size_t)(ks0+rbase+ 8)*NCOL + cols4] : make_float4(0,0,0,0);
        tv2 = cvalid ? *(const float4*)&T[(size_t)(ks0+rbase+16)*NCOL + cols4] : make_float4(0,0,0,0);
        tv3 = cvalid ? *(const float4*)&T[(size_t)(ks0+rbase+24)*NCOL + cols4] : make_float4(0,0,0,0);
        st_bf4(&Ts0[rbase   ][f4c*4], tv0);
        st_bf4(&Ts0[rbase+ 8][f4c*4], tv1);
        st_bf4(&Ts0[rbase+16][f4c*4], tv2);
        st_bf4(&Ts0[rbase+24][f4c*4], tv3);
      }
      __syncthreads();

      for (int s = 0; s < 16; s++) {
        TsRow* Tc = (s & 1) ? Ts1 : Ts0;
        TsRow* Tn = (s & 1) ? Ts0 : Ts1;
        if (s < 15) {
          int ks0 = k0b + (s+1)*32;
          tv0 = cvalid ? *(const float4*)&T[(size_t)(ks0+rbase   )*NCOL + cols4] : make_float4(0,0,0,0);
          tv1 = cvalid ? *(const float4*)&T[(size_t)(ks0+rbase+ 8)*NCOL + cols4] : make_float4(0,0,0,0);
          tv2 = cvalid ? *(const float4*)&T[(size_t)(ks0+rbase+16)*NCOL + cols4] : make_float4(0,0,0,0);
          tv3 = cvalid ? *(const float4*)&T[(size_t)(ks0+rbase+24)*NCOL + cols4] : make_float4(0,0,0,0);
        }
        {
          int k0 = k0b + s*32;
          bf16x8 af[4];
          #pragma unroll
          for (int mf=0; mf<4; mf++) {
            bf16x8 raw = *(const bf16x8*)(h2b + (size_t)(mf*16 + l15)*FLAT + k0 + kg*8);
            __hip_bfloat16 ta[8];
            #pragma unroll
            for (int jj=0; jj<8; jj++) {
              float f = fmaf(bf2f(raw[jj]), sc, sh);
              f = f >= 0.f ? f : 0.2f*f;
              ta[jj] = __float2bfloat16(f);
            }
            af[mf] = *(bf16x8*)ta;
          }
          bf16x8 bfr[2];
          #pragma unroll
          for (int nf=0; nf<2; nf++) {
            int c = wv*32 + nf*16 + l15;
            short tb[8];
            #pragma unroll
            for (int jj=0; jj<8; jj++)
              tb[jj] = Tc[kg*8+jj][c];
            bfr[nf] = *(bf16x8*)tb;
          }
          #pragma unroll
          for (int mf=0;mf<4;mf++)
            #pragma unroll
            for (int nf=0;nf<2;nf++)
              acc[mf][nf] = __builtin_amdgcn_mfma_f32_16x16x32_bf16(af[mf], bfr[nf], acc[mf][nf], 0, 0, 0);
        }
        __syncthreads();
        if (s < 15) {
          st_bf4(&Tn[rbase   ][f4c*4], tv0);
          st_bf4(&Tn[rbase+ 8][f4c*4], tv1);
          st_bf4(&Tn[rbase+16][f4c*4], tv2);
          st_bf4(&Tn[rbase+24][f4c*4], tv3);
          __syncthreads();
        }
      }
      __hip_bfloat16* op = Mpart + (size_t)(kc*4 + ng)*8192;
      #pragma unroll
      for (int mf=0; mf<4; mf++) {
        __hip_bfloat16 buf[8];
        #pragma unroll
        for (int nf=0; nf<2; nf++)
          #pragma unroll
          for (int q=0; q<4; q++)
            buf[nf*4+q] = __float2bfloat16(acc[mf][nf][q]);
        *(bf16x8*)(op + ((size_t)mf*256 + t)*8) = *(bf16x8*)buf;
      }
      return;
    }

    // ================= final1 path =================
    int bx = bid - 1024;          // 0..511 = b*8 + s
    int b = bx >> 3, s = bx & 7;
    double* rA = (double*)smem;                 // [16][16] s1 partials
    double* rB = (double*)(smem + 2048);        // [16][16] s2 partials
    float*  scs = (float*)(smem + 4096);        // 16 floats
    float*  shs = (float*)(smem + 4096 + 64);   // 16 floats
    double* red = (double*)(smem + 8192);       // 256 doubles
    {
      int cl = t >> 4, i = t & 15;
      int c = s*16 + cl;
      double a1 = 0.0, a2 = 0.0;
      #pragma unroll
      for (int q=0;q<16;q++) {
        a1 += bnp2[(size_t)c*256 + i*16 + q];
        a2 += bnp2[32768 + (size_t)c*256 + i*16 + q];
      }
      rA[cl*16+i] = a1; rB[cl*16+i] = a2;
      __syncthreads();
      for (int st = 8; st > 0; st >>= 1) {
        if (i < st) { rA[cl*16+i] += rA[cl*16+i+st]; rB[cl*16+i] += rB[cl*16+i+st]; }
        __syncthreads();
      }
      if (i == 0) {
        double mean = rA[cl*16] * (1.0/65536.0);
        double var  = rB[cl*16] * (1.0/65536.0) - mean*mean;
        double rstd = 1.0 / sqrt(var + 1e-5);
        double scd  = rstd * (double)gamma[c];
        scs[cl] = (float)scd;
        shs[cl] = (float)((double)beta[c] - mean*scd);
      }
      __syncthreads();
    }
    const __hip_bfloat16* hp = h2b + (size_t)b*FLAT;
    double acc = 0.0;
    for (int g = s*2048 + t; g < (s+1)*2048; g += 256) {  // bf16x8 groups
      int k = g*8;
      int cl = (k >> 10) & 15;
      float sc = scs[cl], sh = shs[cl];
      bf16x8 v = *(const bf16x8*)&hp[k];
      float4 w0 = *(const float4*)&lw[k];
      float4 w1 = *(const float4*)&lw[k+4];
      float f0 = fmaf(bf2f(v[0]), sc, sh); f0 = f0>=0.f?f0:0.2f*f0;
      float f1 = fmaf(bf2f(v[1]), sc, sh); f1 = f1>=0.f?f1:0.2f*f1;
      float f2 = fmaf(bf2f(v[2]), sc, sh); f2 = f2>=0.f?f2:0.2f*f2;
      float f3 = fmaf(bf2f(v[3]), sc, sh); f3 = f3>=0.f?f3:0.2f*f3;
      float f4 = fmaf(bf2f(v[4]), sc, sh); f4 = f4>=0.f?f4:0.2f*f4;
      float f5 = fmaf(bf2f(v[5]), sc, sh); f5 = f5>=0.f?f5:0.2f*f5;
      float f6 = fmaf(bf2f(v[6]), sc, sh); f6 = f6>=0.f?f6:0.2f*f6;
      float f7 = fmaf(bf2f(v[7]), sc, sh); f7 = f7>=0.f?f7:0.2f*f7;
      acc = fma((double)f0, (double)w0.x, acc);
      acc = fma((double)f1, (double)w0.y, acc);
      acc = fma((double)f2, (double)w0.z, acc);
      acc = fma((double)f3, (double)w0.w, acc);
      acc = fma((double)f4, (double)w1.x, acc);
      acc = fma((double)f5, (double)w1.y, acc);
      acc = fma((double)f6, (double)w1.z, acc);
      acc = fma((double)f7, (double)w1.w, acc);
    }
    red[t] = acc;
    __syncthreads();
    for (int st = 128; st > 0; st >>= 1) {
      if (t < st) red[t] += red[t + st];
      __syncthreads();
    }
    if (t == 0) fpart[bx] = red[0];
}

// ---------------- mreduce stage A: coalesced 8-chunk partial sums -> Mpart2 fp32 ----------------
__global__ __launch_bounds__(256) void k_mreduceA(const __hip_bfloat16* __restrict__ Mpart,
    float* __restrict__ Mpart2)
{
    int ng = blockIdx.x & 3, kg8 = blockIdx.x >> 2;
    int t = threadIdx.x;
    f32x4 a0[4], a1[4];
    #pragma unroll
    for (int mf=0; mf<4; mf++) { a0[mf] = (f32x4)(0.f); a1[mf] = (f32x4)(0.f); }
    #pragma unroll
    for (int kcl=0; kcl<8; kcl++) {
      int kc = kg8*8 + kcl;
      const __hip_bfloat16* ch = Mpart + (size_t)(kc*4 + ng)*8192;
      #pragma unroll
      for (int mf=0; mf<4; mf++) {
        bf16x8 v = *(const bf16x8*)(ch + ((size_t)mf*256 + t)*8);
        a0[mf][0] += bf2f(v[0]); a0[mf][1] += bf2f(v[1]);
        a0[mf][2] += bf2f(v[2]); a0[mf][3] += bf2f(v[3]);
        a1[mf][0] += bf2f(v[4]); a1[mf][1] += bf2f(v[5]);
        a1[mf][2] += bf2f(v[6]); a1[mf][3] += bf2f(v[7]);
      }
    }
    #pragma unroll
    for (int mf=0; mf<4; mf++) {
      float* dst = Mpart2 + ((size_t)(ng*32 + kg8)*4 + mf)*2048 + t*8;
      *(f32x4*)dst = a0[mf];
      *(f32x4*)(dst+4) = a1[mf];
    }
}

// ---------------- minibatch discrimination: o_b ----------------
__global__ __launch_bounds__(256) void k_ob(const float* __restrict__ Mpart2,
    float* __restrict__ ob)
{
    int o = blockIdx.x;   // 0..99
    __shared__ float Ms[320];
    __shared__ float red[256];
    for (int idx = threadIdx.x; idx < 320; idx += 256) {
      int a = idx / 5, d = idx - a*5;
      int r = a, c = o*5 + d;
      int mf = r >> 4, kg = (r >> 2) & 3, q = r & 3;
      int ng = c >> 7, wv = (c >> 5) & 3, nf = (c >> 4) & 1, l15 = c & 15;
      int t = wv*64 + kg*16 + l15, j8 = nf*4 + q;
      const float* p = Mpart2 + ((size_t)(ng*32)*4 + mf)*2048 + t*8 + j8;
      float s = 0.f;
      #pragma unroll 8
      for (int kg8 = 0; kg8 < 32; kg8++) s += p[(size_t)kg8*8192];
      Ms[idx] = s;
    }
    __syncthreads();
    int b = threadIdx.x & 63, aq = threadIdx.x >> 6;
    float s = 0.f;
    for (int a = aq*16; a < aq*16+16; a++) {
      float n = 0.f;
      #pragma unroll
      for (int d=0; d<5; d++) n += fabsf(Ms[a*5+d] - Ms[b*5+d]);
      s += expf(-n);
    }
    red[threadIdx.x] = s;
    __syncthreads();
    if (threadIdx.x < 64)
      ob[(size_t)b*100 + o] = red[b] + red[64+b] + red[128+b] + red[192+b];
}

__global__ void k_final2(const double* __restrict__ fpart,
    const float* __restrict__ ob, const float* __restrict__ lw,
    const float* __restrict__ lb, float* __restrict__ out)
{
    int b = threadIdx.x;   // 64 threads, 1 block
    double s = 0.0;
    #pragma unroll
    for (int i = 0; i < 8; i++) s += fpart[b*8 + i];
    for (int o = 0; o < 100; o++)
      s = fma((double)ob[(size_t)b*100 + o], (double)lw[FLAT + o], s);
    s += (double)lb[0];
    out[b] = (float)(1.0 / (1.0 + exp(-s)));
}

extern "C" void kernel_launch(void* const* d_in, const int* in_sizes, int n_in,
                              void* d_out, int out_size, void* d_ws, size_t ws_size,
                              hipStream_t stream)
{
    const float* x   = (const float*)d_in[0];
    const float* w1  = (const float*)d_in[1];
    const float* b1  = (const float*)d_in[2];
    const float* w2  = (const float*)d_in[3];
    const float* b2  = (const float*)d_in[4];
    const float* gam = (const float*)d_in[5];
    const float* bet = (const float*)d_in[6];
    const float* T   = (const float*)d_in[7];
    const float* lw  = (const float*)d_in[8];
    const float* lb  = (const float*)d_in[9];
    float* out = (float*)d_out;

    float* ws = (float*)d_ws;
    // Layout (float offsets), ws ~1GB:
    //   [0 .. 8,388,608)            h1 bf16 -> later Mpart bf16 [1024][8192]
    //   [8,388,608 .. 12,582,912)   h2b bf16 [64][131072]
    //   [12,582,912 .. 12,648,448)  Bw bf16
    //   [12,648,704 .. 12,655,104)  ob (6400 f32)
    //   [12,655,104 .. 13,703,680)  Mpart2 (1,048,576 f32)
    //   [13,703,680 .. 13,834,752)  bnp2 (65,536 doubles: s1 [0,32768), s2 [32768,65536))
    //   [13,834,752 .. +1024)       fpart (512 doubles)
    __hip_bfloat16* h1 = (__hip_bfloat16*)ws;
    __hip_bfloat16* Mpart = (__hip_bfloat16*)ws;      // aliases h1 (dead after conv2)
    __hip_bfloat16* h2b = (__hip_bfloat16*)(ws + 8388608);
    __hip_bfloat16* Bw  = (__hip_bfloat16*)(ws + 12582912);
    float* ob    = ws + 12648704;
    float* Mpart2 = ws + 12655104;
    double* bnp2  = (double*)(ws + 13703680);
    double* fpart = (double*)(ws + 13834752);

    k_conv1p<<<1536, 256, 0, stream>>>(x, w1, b1, w2, h1, Bw);
    k_conv2<<<512, 256, 0, stream>>>(h1, Bw, b2, h2b, bnp2);
    k_mgf<<<1536, 256, 0, stream>>>(h2b, bnp2, gam, bet, T, lw, Mpart, fpart);
    k_mreduceA<<<128, 256, 0, stream>>>(Mpart, Mpart2);
    k_ob<<<100, 256, 0, stream>>>(Mpart2, ob);
    k_final2<<<1, 64, 0, stream>>>(fpart, ob, lw, lb, out);
}

// Round 16
// 172.425 us; speedup vs baseline: 1.0613x; 1.0399x over previous
//
#include <hip/hip_runtime.h>
#include <hip/hip_bf16.h>
#include <math.h>

#define BB 64
#define SS 128
#define C1 64
#define H1D 64
#define C2 128
#define H2D 32
#define FLAT 131072
#define NCOL 500
#define KCH 256      // split-K chunks in mgemm (deterministic partials, bf16)
#define KCSZ 512     // k per chunk  (KCH*KCSZ == FLAT)

typedef __attribute__((ext_vector_type(4))) float f32x4;
typedef __attribute__((ext_vector_type(8))) short bf16x8;

__device__ inline float bf2f(short s) {
    union { unsigned int u; float f; } z;
    z.u = ((unsigned int)(unsigned short)s) << 16;
    return z.f;
}

// ---------------- fused: prepw (blocks 0..511) + conv1 (blocks 512..1535) ----------------
__global__ __launch_bounds__(256) void k_conv1p(const float* __restrict__ x,
    const float* __restrict__ w, const float* __restrict__ bias,
    const float* __restrict__ w2,
    __hip_bfloat16* __restrict__ h1, __hip_bfloat16* __restrict__ Bw)
{
    int bid = blockIdx.x;
    if (bid < 512) {
      int i = bid*256 + threadIdx.x;             // 131072
      int jj = i & 7, oc = (i>>3)&127, kl8 = (i>>10)&31, stage = i>>15;
      int kl = kl8*8 + jj;
      int tap = kl >> 4, icl = kl & 15;
      int ic = stage*16 + icl;
      Bw[i] = __float2bfloat16(w2[(size_t)oc*1024 + ic*16 + tap]);
      return;
    }
    int tid = (bid - 512)*256 + threadIdx.x;     // (b, oh, ow)
    int ow = tid & 63, oh = (tid>>6)&63, bi = tid>>12;
    int ih0 = oh*2-1, iw0 = ow*2-1;
    float in[48];
    #pragma unroll
    for (int ic=0; ic<3; ic++)
      #pragma unroll
      for (int kh=0; kh<4; kh++)
        #pragma unroll
        for (int kw=0; kw<4; kw++) {
          int ih = ih0+kh, iw = iw0+kw;
          float v = 0.f;
          if ((unsigned)ih < 128u && (unsigned)iw < 128u)
            v = x[((size_t)(bi*3+ic)*SS + ih)*SS + iw];
          in[ic*16+kh*4+kw] = v;
        }
    #pragma unroll
    for (int g=0; g<4; g++) {
      __hip_bfloat16 outv[16];
      #pragma unroll
      for (int ocl=0; ocl<16; ocl++) {
        int oc = g*16 + ocl;
        float a = bias[oc];
        const float* wp = w + oc*48;             // wave-uniform -> scalar loads
        #pragma unroll
        for (int t=0; t<48; t++) a = fmaf(in[t], wp[t], a);
        a = a >= 0.f ? a : 0.2f*a;
        outv[ocl] = __float2bfloat16(a);
      }
      __hip_bfloat16* dst = h1 + (((size_t)g*BB + bi)*4096 + oh*64 + ow)*16;
      *(bf16x8*)(dst)     = *(bf16x8*)&outv[0];
      *(bf16x8*)(dst + 8) = *(bf16x8*)&outv[8];
    }
}

// ---------------- conv2 MFMA implicit GEMM -> h2b bf16; + per-block BN partials ----------------
// XCD pairing: nh = (bid>>3)&1 so the two nh-halves of one (bi,strip) share
// bid%8 -> same XCD -> second h1 staging pass hits L2.
__global__ __launch_bounds__(256) void k_conv2(const __hip_bfloat16* __restrict__ h1,
    const __hip_bfloat16* __restrict__ Bw, const float* __restrict__ b2,
    __hip_bfloat16* __restrict__ h2b, double* __restrict__ bnp2)
{
    int bid = blockIdx.x;
    int nh = (bid >> 3) & 1;
    int pair = (bid >> 4)*8 + (bid & 7);         // 0..255
    int bi = pair >> 2, strip = pair & 3;
    int lane = threadIdx.x & 63, wv = threadIdx.x >> 6;
    int l15 = lane & 15, kg = lane >> 4;

    __shared__ __align__(16) short tile[36*33*24];   // 57 KB
    __shared__ float2 bnl[4][16][16];                // 8 KB

    f32x4 acc[4][4];
    #pragma unroll
    for (int m=0;m<4;m++)
      #pragma unroll
      for (int n=0;n<4;n++) acc[m][n] = (f32x4)(0.f);

    int ihb = strip*16 - 1;

    for (int stage=0; stage<4; ++stage) {
      const __hip_bfloat16* hsrc = h1 + ((size_t)stage*BB + bi)*4096*16;
      for (int idx = threadIdx.x; idx < 2376; idx += 256) {
        int half = idx & 1, p = idx >> 1;        // p = ih_l*66 + iw_l
        int ih_l = p / 66, iw_l = p - ih_l*66;
        int ih = ihb + ih_l, iw = iw_l - 1;
        int row48 = (ih_l*2 + (iw_l&1))*33 + (iw_l>>1);
        bf16x8 v = (bf16x8)(0);
        if ((unsigned)ih < 64u && (unsigned)iw < 64u)
          v = *(const bf16x8*)(hsrc + ((size_t)(ih*64+iw)*16 + half*8));
        *(bf16x8*)&tile[row48*24 + half*8] = v;
      }
      __syncthreads();
      const __hip_bfloat16* bwst = Bw + (size_t)stage*32*128*8;
      #pragma unroll
      for (int j=0; j<8; j++) {
        bf16x8 bf[4];
        #pragma unroll
        for (int nf=0; nf<4; nf++)
          bf[nf] = *(const bf16x8*)(bwst + ((size_t)((j*4+kg)*128) + nh*64 + nf*16 + l15)*8);
        int tap = 2*j + (kg>>1);
        int kh = tap>>2, kw = tap&3;
        int icl0 = (kg&1)*8;
        bf16x8 af[4];
        #pragma unroll
        for (int mf=0; mf<4; mf++) {
          int oh_l = 2*wv + (mf>>1);
          int ow   = (mf&1)*16 + l15;
          int ih_l = 2*oh_l + kh;
          int iw_l = 2*ow + kw;
          int row48 = (ih_l*2 + (iw_l&1))*33 + (iw_l>>1);
          af[mf] = *(const bf16x8*)&tile[row48*24 + icl0];
        }
        #pragma unroll
        for (int mf=0; mf<4; mf++)
          #pragma unroll
          for (int nf=0; nf<4; nf++)
            acc[mf][nf] = __builtin_amdgcn_mfma_f32_16x16x32_bf16(af[mf], bf[nf], acc[mf][nf], 0, 0, 0);
      }
      __syncthreads();
    }
    #pragma unroll
    for (int nf=0; nf<4; nf++) {
      int oc = nh*64 + nf*16 + l15;
      float bv = b2[oc];
      float s1 = 0.f, s2 = 0.f;
      #pragma unroll
      for (int mf=0; mf<4; mf++) {
        int p0 = wv*64 + mf*16 + kg*4;
        float v0 = acc[mf][nf][0] + bv;
        float v1 = acc[mf][nf][1] + bv;
        float v2 = acc[mf][nf][2] + bv;
        float v3 = acc[mf][nf][3] + bv;
        s1 += v0+v1+v2+v3;
        s2 = fmaf(v0,v0, fmaf(v1,v1, fmaf(v2,v2, fmaf(v3,v3, s2))));
        __hip_bfloat16 o4[4];
        o4[0] = __float2bfloat16(v0); o4[1] = __float2bfloat16(v1);
        o4[2] = __float2bfloat16(v2); o4[3] = __float2bfloat16(v3);
        *(double*)&h2b[((size_t)bi*C2 + oc)*1024 + strip*256 + p0] = *(double*)o4;
      }
      bnl[nf][wv*4+kg][l15] = make_float2(s1, s2);
    }
    __syncthreads();
    if (threadIdx.x < 64) {
      int nf = threadIdx.x >> 4, l = threadIdx.x & 15;
      double s1 = 0.0, s2 = 0.0;
      #pragma unroll
      for (int i=0;i<16;i++) {
        float2 v = bnl[nf][i][l];
        s1 += (double)v.x; s2 += (double)v.y;
      }
      int oc = nh*64 + nf*16 + l;                // 0..127
      bnp2[(size_t)oc*256 + pair]         = s1;  // s1 bank [0,32768)
      bnp2[32768 + (size_t)oc*256 + pair] = s2;  // s2 bank [32768,65536)
    }
}

// ---------------- fused: mgemm (blocks 0..1023) + final1 (blocks 1024..1535) ----------------
// Both consume {h2b, bnp2}; BN stats computed inline per block.
__global__ __launch_bounds__(256) void k_mgf(const __hip_bfloat16* __restrict__ h2b,
    const double* __restrict__ bnp2, const float* __restrict__ gamma,
    const float* __restrict__ beta, const float* __restrict__ T,
    const float* __restrict__ lw,
    __hip_bfloat16* __restrict__ Mpart, double* __restrict__ fpart)
{
    __shared__ __align__(16) char smem[38432];
    int t = threadIdx.x;
    int bid = blockIdx.x;

    if (bid < 1024) {
      // ================= mgemm path =================
      int lane = t & 63, wv = t >> 6;
      int l15 = lane & 15, kg = lane >> 4;
      int xc = bid & 7, j = bid >> 3;
      int kc = xc*32 + (j >> 2);
      int ng = j & 3;
      int k0b = kc * KCSZ;
      int ch = kc >> 1;

      // inline BN stats for channel ch (LDS region beyond Ts)
      double* r1 = (double*)(smem + 34304);
      double* r2 = (double*)(smem + 34304 + 2048);
      float*  stf = (float*)(smem + 34304 + 4096);
      r1[t] = bnp2[(size_t)ch*256 + t];
      r2[t] = bnp2[32768 + (size_t)ch*256 + t];
      __syncthreads();
      for (int st = 128; st > 0; st >>= 1) {
        if (t < st) { r1[t] += r1[t+st]; r2[t] += r2[t+st]; }
        __syncthreads();
      }
      if (t == 0) {
        double mean = r1[0] * (1.0/65536.0);
        double var  = r2[0] * (1.0/65536.0) - mean*mean;
        double rstd = 1.0 / sqrt(var + 1e-5);
        double scd  = rstd * (double)gamma[ch];
        stf[0] = (float)scd;
        stf[1] = (float)((double)beta[ch] - mean*scd);
      }
      __syncthreads();
      float sc = stf[0], sh = stf[1];

      typedef float TsRow[134];
      TsRow* Ts0 = (TsRow*)smem;          // Ts[2][32][134] overlay
      TsRow* Ts1 = (TsRow*)(smem + 32*134*4);

      int f4c = t & 31, rbase = t >> 5;
      int cols4 = ng*128 + f4c*4;
      bool cvalid = cols4 < 500;

      f32x4 acc[4][2];
      #pragma unroll
      for (int m=0;m<4;m++) { acc[m][0] = (f32x4)(0.f); acc[m][1] = (f32x4)(0.f); }

      float4 tv0, tv1, tv2, tv3;
      {
        int ks0 = k0b;
        tv0 = cvalid ? *(const float4*)&T[(size_t)(ks0+rbase   )*NCOL + cols4] : make_float4(0,0,0,0);
        tv1 = cvalid ? *(const float4*)&T[(size_t)(ks0+rbase+ 8)*NCOL + cols4] : make_float4(0,0,0,0);
        tv2 = cvalid ? *(const float4*)&T[(size_t)(ks0+rbase+16)*NCOL + cols4] : make_float4(0,0,0,0);
        tv3 = cvalid ? *(const float4*)&T[(size_t)(ks0+rbase+24)*NCOL + cols4] : make_float4(0,0,0,0);
        float* d0 = &Ts0[rbase   ][f4c*4];
        float* d1 = &Ts0[rbase+ 8][f4c*4];
        float* d2 = &Ts0[rbase+16][f4c*4];
        float* d3 = &Ts0[rbase+24][f4c*4];
        *(float2*)d0 = make_float2(tv0.x,tv0.y); *(float2*)(d0+2) = make_float2(tv0.z,tv0.w);
        *(float2*)d1 = make_float2(tv1.x,tv1.y); *(float2*)(d1+2) = make_float2(tv1.z,tv1.w);
        *(float2*)d2 = make_float2(tv2.x,tv2.y); *(float2*)(d2+2) = make_float2(tv2.z,tv2.w);
        *(float2*)d3 = make_float2(tv3.x,tv3.y); *(float2*)(d3+2) = make_float2(tv3.z,tv3.w);
      }
      __syncthreads();

      for (int s = 0; s < 16; s++) {
        TsRow* Tc = (s & 1) ? Ts1 : Ts0;
        TsRow* Tn = (s & 1) ? Ts0 : Ts1;
        if (s < 15) {
          int ks0 = k0b + (s+1)*32;
          tv0 = cvalid ? *(const float4*)&T[(size_t)(ks0+rbase   )*NCOL + cols4] : make_float4(0,0,0,0);
          tv1 = cvalid ? *(const float4*)&T[(size_t)(ks0+rbase+ 8)*NCOL + cols4] : make_float4(0,0,0,0);
          tv2 = cvalid ? *(const float4*)&T[(size_t)(ks0+rbase+16)*NCOL + cols4] : make_float4(0,0,0,0);
          tv3 = cvalid ? *(const float4*)&T[(size_t)(ks0+rbase+24)*NCOL + cols4] : make_float4(0,0,0,0);
        }
        {
          int k0 = k0b + s*32;
          bf16x8 af[4];
          #pragma unroll
          for (int mf=0; mf<4; mf++) {
            bf16x8 raw = *(const bf16x8*)(h2b + (size_t)(mf*16 + l15)*FLAT + k0 + kg*8);
            __hip_bfloat16 ta[8];
            #pragma unroll
            for (int jj=0; jj<8; jj++) {
              float f = fmaf(bf2f(raw[jj]), sc, sh);
              f = f >= 0.f ? f : 0.2f*f;
              ta[jj] = __float2bfloat16(f);
            }
            af[mf] = *(bf16x8*)ta;
          }
          bf16x8 bfr[2];
          #pragma unroll
          for (int nf=0; nf<2; nf++) {
            int c = wv*32 + nf*16 + l15;
            __hip_bfloat16 tb[8];
            #pragma unroll
            for (int jj=0; jj<8; jj++)
              tb[jj] = __float2bfloat16(Tc[kg*8+jj][c]);
            bfr[nf] = *(bf16x8*)tb;
          }
          #pragma unroll
          for (int mf=0;mf<4;mf++)
            #pragma unroll
            for (int nf=0;nf<2;nf++)
              acc[mf][nf] = __builtin_amdgcn_mfma_f32_16x16x32_bf16(af[mf], bfr[nf], acc[mf][nf], 0, 0, 0);
        }
        __syncthreads();
        if (s < 15) {
          float* d0 = &Tn[rbase   ][f4c*4];
          float* d1 = &Tn[rbase+ 8][f4c*4];
          float* d2 = &Tn[rbase+16][f4c*4];
          float* d3 = &Tn[rbase+24][f4c*4];
          *(float2*)d0 = make_float2(tv0.x,tv0.y); *(float2*)(d0+2) = make_float2(tv0.z,tv0.w);
          *(float2*)d1 = make_float2(tv1.x,tv1.y); *(float2*)(d1+2) = make_float2(tv1.z,tv1.w);
          *(float2*)d2 = make_float2(tv2.x,tv2.y); *(float2*)(d2+2) = make_float2(tv2.z,tv2.w);
          *(float2*)d3 = make_float2(tv3.x,tv3.y); *(float2*)(d3+2) = make_float2(tv3.z,tv3.w);
          __syncthreads();
        }
      }
      __hip_bfloat16* op = Mpart + (size_t)(kc*4 + ng)*8192;
      #pragma unroll
      for (int mf=0; mf<4; mf++) {
        __hip_bfloat16 buf[8];
        #pragma unroll
        for (int nf=0; nf<2; nf++)
          #pragma unroll
          for (int q=0; q<4; q++)
            buf[nf*4+q] = __float2bfloat16(acc[mf][nf][q]);
        *(bf16x8*)(op + ((size_t)mf*256 + t)*8) = *(bf16x8*)buf;
      }
      return;
    }

    // ================= final1 path =================
    int bx = bid - 1024;          // 0..511 = b*8 + s
    int b = bx >> 3, s = bx & 7;
    double* rA = (double*)smem;                 // [16][16] s1 partials
    double* rB = (double*)(smem + 2048);        // [16][16] s2 partials
    float*  scs = (float*)(smem + 4096);        // 16 floats
    float*  shs = (float*)(smem + 4096 + 64);   // 16 floats
    double* red = (double*)(smem + 8192);       // 256 doubles
    {
      int cl = t >> 4, i = t & 15;
      int c = s*16 + cl;
      double a1 = 0.0, a2 = 0.0;
      #pragma unroll
      for (int q=0;q<16;q++) {
        a1 += bnp2[(size_t)c*256 + i*16 + q];
        a2 += bnp2[32768 + (size_t)c*256 + i*16 + q];
      }
      rA[cl*16+i] = a1; rB[cl*16+i] = a2;
      __syncthreads();
      for (int st = 8; st > 0; st >>= 1) {
        if (i < st) { rA[cl*16+i] += rA[cl*16+i+st]; rB[cl*16+i] += rB[cl*16+i+st]; }
        __syncthreads();
      }
      if (i == 0) {
        double mean = rA[cl*16] * (1.0/65536.0);
        double var  = rB[cl*16] * (1.0/65536.0) - mean*mean;
        double rstd = 1.0 / sqrt(var + 1e-5);
        double scd  = rstd * (double)gamma[c];
        scs[cl] = (float)scd;
        shs[cl] = (float)((double)beta[c] - mean*scd);
      }
      __syncthreads();
    }
    const __hip_bfloat16* hp = h2b + (size_t)b*FLAT;
    double acc = 0.0;
    for (int g = s*2048 + t; g < (s+1)*2048; g += 256) {  // bf16x8 groups
      int k = g*8;
      int cl = (k >> 10) & 15;
      float sc = scs[cl], sh = shs[cl];
      bf16x8 v = *(const bf16x8*)&hp[k];
      float4 w0 = *(const float4*)&lw[k];
      float4 w1 = *(const float4*)&lw[k+4];
      float f0 = fmaf(bf2f(v[0]), sc, sh); f0 = f0>=0.f?f0:0.2f*f0;
      float f1 = fmaf(bf2f(v[1]), sc, sh); f1 = f1>=0.f?f1:0.2f*f1;
      float f2 = fmaf(bf2f(v[2]), sc, sh); f2 = f2>=0.f?f2:0.2f*f2;
      float f3 = fmaf(bf2f(v[3]), sc, sh); f3 = f3>=0.f?f3:0.2f*f3;
      float f4 = fmaf(bf2f(v[4]), sc, sh); f4 = f4>=0.f?f4:0.2f*f4;
      float f5 = fmaf(bf2f(v[5]), sc, sh); f5 = f5>=0.f?f5:0.2f*f5;
      float f6 = fmaf(bf2f(v[6]), sc, sh); f6 = f6>=0.f?f6:0.2f*f6;
      float f7 = fmaf(bf2f(v[7]), sc, sh); f7 = f7>=0.f?f7:0.2f*f7;
      acc = fma((double)f0, (double)w0.x, acc);
      acc = fma((double)f1, (double)w0.y, acc);
      acc = fma((double)f2, (double)w0.z, acc);
      acc = fma((double)f3, (double)w0.w, acc);
      acc = fma((double)f4, (double)w1.x, acc);
      acc = fma((double)f5, (double)w1.y, acc);
      acc = fma((double)f6, (double)w1.z, acc);
      acc = fma((double)f7, (double)w1.w, acc);
    }
    red[t] = acc;
    __syncthreads();
    for (int st = 128; st > 0; st >>= 1) {
      if (t < st) red[t] += red[t + st];
      __syncthreads();
    }
    if (t == 0) fpart[bx] = red[0];
}

// ---------------- mreduce stage A: coalesced 8-chunk partial sums -> Mpart2 fp32 ----------------
__global__ __launch_bounds__(256) void k_mreduceA(const __hip_bfloat16* __restrict__ Mpart,
    float* __restrict__ Mpart2)
{
    int ng = blockIdx.x & 3, kg8 = blockIdx.x >> 2;
    int t = threadIdx.x;
    f32x4 a0[4], a1[4];
    #pragma unroll
    for (int mf=0; mf<4; mf++) { a0[mf] = (f32x4)(0.f); a1[mf] = (f32x4)(0.f); }
    #pragma unroll
    for (int kcl=0; kcl<8; kcl++) {
      int kc = kg8*8 + kcl;
      const __hip_bfloat16* ch = Mpart + (size_t)(kc*4 + ng)*8192;
      #pragma unroll
      for (int mf=0; mf<4; mf++) {
        bf16x8 v = *(const bf16x8*)(ch + ((size_t)mf*256 + t)*8);
        a0[mf][0] += bf2f(v[0]); a0[mf][1] += bf2f(v[1]);
        a0[mf][2] += bf2f(v[2]); a0[mf][3] += bf2f(v[3]);
        a1[mf][0] += bf2f(v[4]); a1[mf][1] += bf2f(v[5]);
        a1[mf][2] += bf2f(v[6]); a1[mf][3] += bf2f(v[7]);
      }
    }
    #pragma unroll
    for (int mf=0; mf<4; mf++) {
      float* dst = Mpart2 + ((size_t)(ng*32 + kg8)*4 + mf)*2048 + t*8;
      *(f32x4*)dst = a0[mf];
      *(f32x4*)(dst+4) = a1[mf];
    }
}

// ---------------- minibatch discrimination: o_b ----------------
__global__ __launch_bounds__(256) void k_ob(const float* __restrict__ Mpart2,
    float* __restrict__ ob)
{
    int o = blockIdx.x;   // 0..99
    __shared__ float Ms[320];
    __shared__ float red[256];
    for (int idx = threadIdx.x; idx < 320; idx += 256) {
      int a = idx / 5, d = idx - a*5;
      int r = a, c = o*5 + d;
      int mf = r >> 4, kg = (r >> 2) & 3, q = r & 3;
      int ng = c >> 7, wv = (c >> 5) & 3, nf = (c >> 4) & 1, l15 = c & 15;
      int t = wv*64 + kg*16 + l15, j8 = nf*4 + q;
      const float* p = Mpart2 + ((size_t)(ng*32)*4 + mf)*2048 + t*8 + j8;
      float s = 0.f;
      #pragma unroll 8
      for (int kg8 = 0; kg8 < 32; kg8++) s += p[(size_t)kg8*8192];
      Ms[idx] = s;
    }
    __syncthreads();
    int b = threadIdx.x & 63, aq = threadIdx.x >> 6;
    float s = 0.f;
    for (int a = aq*16; a < aq*16+16; a++) {
      float n = 0.f;
      #pragma unroll
      for (int d=0; d<5; d++) n += fabsf(Ms[a*5+d] - Ms[b*5+d]);
      s += expf(-n);
    }
    red[threadIdx.x] = s;
    __syncthreads();
    if (threadIdx.x < 64)
      ob[(size_t)b*100 + o] = red[b] + red[64+b] + red[128+b] + red[192+b];
}

__global__ void k_final2(const double* __restrict__ fpart,
    const float* __restrict__ ob, const float* __restrict__ lw,
    const float* __restrict__ lb, float* __restrict__ out)
{
    int b = threadIdx.x;   // 64 threads, 1 block
    double s = 0.0;
    #pragma unroll
    for (int i = 0; i < 8; i++) s += fpart[b*8 + i];
    for (int o = 0; o < 100; o++)
      s = fma((double)ob[(size_t)b*100 + o], (double)lw[FLAT + o], s);
    s += (double)lb[0];
    out[b] = (float)(1.0 / (1.0 + exp(-s)));
}

extern "C" void kernel_launch(void* const* d_in, const int* in_sizes, int n_in,
                              void* d_out, int out_size, void* d_ws, size_t ws_size,
                              hipStream_t stream)
{
    const float* x   = (const float*)d_in[0];
    const float* w1  = (const float*)d_in[1];
    const float* b1  = (const float*)d_in[2];
    const float* w2  = (const float*)d_in[3];
    const float* b2  = (const float*)d_in[4];
    const float* gam = (const float*)d_in[5];
    const float* bet = (const float*)d_in[6];
    const float* T   = (const float*)d_in[7];
    const float* lw  = (const float*)d_in[8];
    const float* lb  = (const float*)d_in[9];
    float* out = (float*)d_out;

    float* ws = (float*)d_ws;
    // Layout (float offsets), ws ~1GB:
    //   [0 .. 8,388,608)            h1 bf16 -> later Mpart bf16 [1024][8192]
    //   [8,388,608 .. 12,582,912)   h2b bf16 [64][131072]
    //   [12,582,912 .. 12,648,448)  Bw bf16
    //   [12,648,704 .. 12,655,104)  ob (6400 f32)
    //   [12,655,104 .. 13,703,680)  Mpart2 (1,048,576 f32)
    //   [13,703,680 .. 13,834,752)  bnp2 (65,536 doubles: s1 [0,32768), s2 [32768,65536))
    //   [13,834,752 .. +1024)       fpart (512 doubles)
    __hip_bfloat16* h1 = (__hip_bfloat16*)ws;
    __hip_bfloat16* Mpart = (__hip_bfloat16*)ws;      // aliases h1 (dead after conv2)
    __hip_bfloat16* h2b = (__hip_bfloat16*)(ws + 8388608);
    __hip_bfloat16* Bw  = (__hip_bfloat16*)(ws + 12582912);
    float* ob    = ws + 12648704;
    float* Mpart2 = ws + 12655104;
    double* bnp2  = (double*)(ws + 13703680);
    double* fpart = (double*)(ws + 13834752);

    k_conv1p<<<1536, 256, 0, stream>>>(x, w1, b1, w2, h1, Bw);
    k_conv2<<<512, 256, 0, stream>>>(h1, Bw, b2, h2b, bnp2);
    k_mgf<<<1536, 256, 0, stream>>>(h2b, bnp2, gam, bet, T, lw, Mpart, fpart);
    k_mreduceA<<<128, 256, 0, stream>>>(Mpart, Mpart2);
    k_ob<<<100, 256, 0, stream>>>(Mpart2, ob);
    k_final2<<<1, 64, 0, stream>>>(fpart, ob, lw, lb, out);
}